// Round 13
// baseline (522.779 us; speedup 1.0000x reference)
//
#include <hip/hip_runtime.h>
#include <hip/hip_bf16.h>
#include <math.h>

#define NFRM 8192   // B*T
#define NPT  128    // N points
#define CH   128    // HID
#define DD   256    // D
#define HH   512    // H
#define SS   16     // S
#define NL   4

typedef __attribute__((ext_vector_type(8))) short bf16x8;
typedef __attribute__((ext_vector_type(4))) float f32x4;
typedef unsigned short u16;

#define MFMA16 __builtin_amdgcn_mfma_f32_16x16x32_bf16

// ---------------- helpers ----------------

__device__ __forceinline__ float red256(float v, int tid, volatile float* sc) {
#pragma unroll
  for (int off = 32; off; off >>= 1) v += __shfl_down(v, off);
  __syncthreads();
  if ((tid & 63) == 0) sc[tid >> 6] = v;
  __syncthreads();
  return sc[0] + sc[1] + sc[2] + sc[3];
}

__device__ __forceinline__ float sigmoidf_(float x) { return 1.f / (1.f + __expf(-x)); }
__device__ __forceinline__ float geluf_(float x) { return 0.5f * x * (1.f + erff(x * 0.70710678118654752f)); }

__device__ __forceinline__ u16 f2bf(float f) {
  __hip_bfloat16 h = __float2bfloat16(f);
  return *(u16*)&h;
}
__device__ __forceinline__ float bf2f(u16 u) {
  union { unsigned int i; float f; } v; v.i = ((unsigned int)u) << 16; return v.f;
}

// ---------------- kernels ----------------

// pack weights (vectorized casts). BmTd[l][d][s][h] = cw[l][h][d]*Bm[l][h][s]; cbB[l][s] = sum_h cb*Bm
__global__ __launch_bounds__(256) void k_prep(const float* __restrict__ conv2_w,
    const float* __restrict__ fproj_w, const float* __restrict__ in_w, const float* __restrict__ out_w,
    const float* __restrict__ A, const float* __restrict__ Bm,
    const float* __restrict__ cw, const float* __restrict__ cb,
    u16* __restrict__ W2B, u16* __restrict__ fprojB, u16* __restrict__ inwB,
    u16* __restrict__ outwB, u16* __restrict__ albB, u16* __restrict__ BmTd,
    float* __restrict__ cbB) {
  int idx = blockIdx.x * 256 + threadIdx.x;
  if (idx < 16384) {
    int c = idx >> 7, k = idx & 127;
    int dst = c * 128 + ((((k >> 3) ^ (c & 7)) << 3) | (k & 7));
    W2B[dst] = f2bf(conv2_w[idx]);
    return;
  }
  idx -= 16384;
  if (idx < 8192) {            // fprojB
    float4 v = ((const float4*)fproj_w)[idx];
    ushort4 o; o.x = f2bf(v.x); o.y = f2bf(v.y); o.z = f2bf(v.z); o.w = f2bf(v.w);
    ((ushort4*)fprojB)[idx] = o;
    return;
  }
  idx -= 8192;
  if (idx < 262144) {          // inwB
    float4 v = ((const float4*)in_w)[idx];
    ushort4 o; o.x = f2bf(v.x); o.y = f2bf(v.y); o.z = f2bf(v.z); o.w = f2bf(v.w);
    ((ushort4*)inwB)[idx] = o;
    return;
  }
  idx -= 262144;
  if (idx < 131072) {          // outwB
    float4 v = ((const float4*)out_w)[idx];
    ushort4 o; o.x = f2bf(v.x); o.y = f2bf(v.y); o.z = f2bf(v.z); o.w = f2bf(v.w);
    ((ushort4*)outwB)[idx] = o;
    return;
  }
  idx -= 131072;
  if (idx < 65536) {
    int l = idx >> 14, rem = idx & 16383, h = rem >> 5, kk = rem & 31;
    albB[idx] = (kk < 16) ? f2bf(A[(size_t)l * 8192 + h * 16 + kk]) : (u16)0;
    return;
  }
  idx -= 65536;
  if (idx < 131072) {
    int l = idx >> 15, rem = idx & 32767;
    int d = rem >> 13, rem2 = rem & 8191, s = rem2 >> 9, h = rem2 & 511;
    BmTd[idx] = f2bf(cw[(size_t)l * 2048 + h * 4 + d] * Bm[(size_t)l * 8192 + h * 16 + s]);
    return;
  }
  idx -= 131072;
  if (idx < 4096) {           // one wave per (l,s)
    int wsl = idx >> 6, lane = idx & 63;
    int l = wsl >> 4, s = wsl & 15;
    float acc = 0.f;
    for (int h = lane; h < 512; h += 64)
      acc = fmaf(cb[l * 512 + h], Bm[(size_t)l * 8192 + h * 16 + s], acc);
#pragma unroll
    for (int off = 32; off; off >>= 1) acc += __shfl_down(acc, off);
    if (lane == 0) cbB[wsl] = acc;
  }
}

// per-frame moments + per-block partials; LAST block folds bn1 constants (old k_stats2)
__global__ __launch_bounds__(256) void k_mom(const float* __restrict__ x, float* __restrict__ msd,
    float* __restrict__ pstat, const float* __restrict__ w1, const float* __restrict__ bw,
    const float* __restrict__ bb, float* __restrict__ cc, unsigned int* __restrict__ cnt) {
  __shared__ float mpart[4][6];
  __shared__ float part2[32][8];
  __shared__ float Mt[8];
  __shared__ unsigned int lastv;
  int tid = threadIdx.x, lane = tid & 63, w = tid >> 6;
  int f = blockIdx.x * 4 + w;
  const float* xf = x + (size_t)f * 384 + lane * 6;
  float a0 = xf[0], a1 = xf[1], a2 = xf[2], b0 = xf[3], b1 = xf[4], b2 = xf[5];
  float s0 = a0 + b0, s1 = a1 + b1, s2 = a2 + b2;
  float p00 = a0*a0 + b0*b0, p01 = a0*a1 + b0*b1, p02 = a0*a2 + b0*b2;
  float p11 = a1*a1 + b1*b1, p12 = a1*a2 + b1*b2, p22 = a2*a2 + b2*b2;
#pragma unroll
  for (int off = 32; off; off >>= 1) {
    s0 += __shfl_down(s0, off); s1 += __shfl_down(s1, off); s2 += __shfl_down(s2, off);
    p00 += __shfl_down(p00, off); p01 += __shfl_down(p01, off); p02 += __shfl_down(p02, off);
    p11 += __shfl_down(p11, off); p12 += __shfl_down(p12, off); p22 += __shfl_down(p22, off);
  }
  if (lane == 0) {
    float mu0 = s0 * (1.f/128.f), mu1 = s1 * (1.f/128.f), mu2 = s2 * (1.f/128.f);
    float C00 = p00 - 128.f*mu0*mu0, C01 = p01 - 128.f*mu0*mu1, C02 = p02 - 128.f*mu0*mu2;
    float C11 = p11 - 128.f*mu1*mu1, C12 = p12 - 128.f*mu1*mu2, C22 = p22 - 128.f*mu2*mu2;
    float sd0 = sqrtf(C00 * (1.f/127.f)) + 1e-10f;
    float sd1 = sqrtf(C11 * (1.f/127.f)) + 1e-10f;
    float sd2 = sqrtf(C22 * (1.f/127.f)) + 1e-10f;
    mpart[w][0] = C00/(sd0*sd0); mpart[w][1] = C01/(sd0*sd1); mpart[w][2] = C02/(sd0*sd2);
    mpart[w][3] = C11/(sd1*sd1); mpart[w][4] = C12/(sd1*sd2); mpart[w][5] = C22/(sd2*sd2);
    float* d = msd + (size_t)f * 8;
    d[0] = mu0; d[1] = mu1; d[2] = mu2; d[3] = 0.f;
    d[4] = 1.f/sd0; d[5] = 1.f/sd1; d[6] = 1.f/sd2; d[7] = 0.f;
  }
  __syncthreads();
  if (tid < 8) {
    float tot = 0.f;
    if (tid < 6) { for (int w2 = 0; w2 < 4; ++w2) tot += mpart[w2][tid]; }
    pstat[blockIdx.x * 8 + tid] = tot;
  }
  __threadfence();
  __syncthreads();
  if (tid == 0) lastv = atomicAdd(cnt, 1u);
  __syncthreads();
  if (lastv != gridDim.x - 1) return;
  // ---- last block: fold bn1 channel constants ----
  {
    int j = tid & 7, g = tid >> 3;
    float sm = 0.f;
    for (int r = g; r < 2048; r += 32) sm += pstat[r * 8 + j];
    part2[g][j] = sm;
    __syncthreads();
    if (tid < 8) { float tot = 0.f; for (int g2 = 0; g2 < 32; ++g2) tot += part2[g2][tid]; Mt[tid] = tot; }
    __syncthreads();
    if (tid < 128) {
      float w0 = w1[tid*3], wa = w1[tid*3+1], wb = w1[tid*3+2];
      float var = (w0*w0*Mt[0] + wa*wa*Mt[3] + wb*wb*Mt[5]
                 + 2.f*(w0*wa*Mt[1] + w0*wb*Mt[2] + wa*wb*Mt[4])) * (1.f/1048576.f);
      float s = bw[tid] / sqrtf(var + 1e-5f);
      ((float4*)cc)[tid] = make_float4(s*w0, s*wa, s*wb, bb[tid]);
    }
  }
}

// main fused kernel: 4 frames/block; parity stats LDS (1 barrier/frame); x prefetch
__global__ __launch_bounds__(256) void k2_main(const float* __restrict__ x, const float4* __restrict__ cc,
    const float4* __restrict__ msd4, const u16* __restrict__ W2B,
    float* __restrict__ z2mx, float* __restrict__ z2mn,
    float* __restrict__ psum, float* __restrict__ psq) {
  __shared__ alignas(16) u16 w2s[16384];     // 32KB, pre-swizzled
  __shared__ float4 ccs[144];                // stride-9 pad
  __shared__ float smx[2][4][CH], smn[2][4][CH], ssm[2][4][CH], ssq[2][4][CH];
  int tid = threadIdx.x;
  for (int i = tid; i < 2048; i += 256) ((float4*)w2s)[i] = ((const float4*)W2B)[i];
  if (tid < 128) ccs[tid + (tid >> 3)] = cc[tid];
  int lane = tid & 63, w = tid >> 6;
  int lr = lane & 15, kg = lane >> 4;
  int row0 = w * 32 + lr, row1 = row0 + 16;
  int f0i = blockIdx.x * 4;
  float4 mu4 = msd4[f0i * 2], rs4 = msd4[f0i * 2 + 1];
  const float* xr0 = x + (size_t)f0i * 384 + row0 * 3;
  const float* xr1 = x + (size_t)f0i * 384 + row1 * 3;
  float cx0 = xr0[0], cx1 = xr0[1], cx2 = xr0[2];
  float cx3 = xr1[0], cx4 = xr1[1], cx5 = xr1[2];
  __syncthreads();
  for (int fi = 0; fi < 4; ++fi) {
    int f = blockIdx.x * 4 + fi;
    int p = fi & 1;
    float xa0 = (cx0 - mu4.x) * rs4.x, xa1 = (cx1 - mu4.y) * rs4.y, xa2 = (cx2 - mu4.z) * rs4.z;
    float xb0 = (cx3 - mu4.x) * rs4.x, xb1 = (cx4 - mu4.y) * rs4.y, xb2 = (cx5 - mu4.z) * rs4.z;
    int fn = (f + 1 < NFRM) ? f + 1 : f;
    float4 nmu = msd4[fn * 2], nrs = msd4[fn * 2 + 1];
    const float* nr0 = x + (size_t)fn * 384 + row0 * 3;
    const float* nr1 = x + (size_t)fn * 384 + row1 * 3;
    float nx0 = nr0[0], nx1 = nr0[1], nx2 = nr0[2];
    float nx3 = nr1[0], nx4 = nr1[1], nx5 = nr1[2];
    f32x4 acc[2][8];
#pragma unroll
    for (int fr = 0; fr < 2; ++fr)
#pragma unroll
      for (int fc = 0; fc < 8; ++fc) acc[fr][fc] = (f32x4){0.f, 0.f, 0.f, 0.f};
#pragma unroll
    for (int ks = 0; ks < 4; ++ks) {
      int kc = ks * 4 + kg;
      int base9 = kc * 9;
      bf16x8 a0, a1;
#pragma unroll
      for (int q = 0; q < 8; ++q) {
        float4 c4 = ccs[base9 + q];
        float h0 = fmaxf(0.f, fmaf(xa0, c4.x, fmaf(xa1, c4.y, fmaf(xa2, c4.z, c4.w))));
        float h1 = fmaxf(0.f, fmaf(xb0, c4.x, fmaf(xb1, c4.y, fmaf(xb2, c4.z, c4.w))));
        a0[q] = (short)f2bf(h0); a1[q] = (short)f2bf(h1);
      }
#pragma unroll
      for (int fc = 0; fc < 8; ++fc) {
        int col = fc * 16 + lr;
        bf16x8 b = *(const bf16x8*)&w2s[col * 128 + ((kc ^ (col & 7)) << 3)];
        acc[0][fc] = MFMA16(a0, b, acc[0][fc], 0, 0, 0);
        acc[1][fc] = MFMA16(a1, b, acc[1][fc], 0, 0, 0);
      }
    }
#pragma unroll
    for (int fc = 0; fc < 8; ++fc) {
      float mx = -3e38f, mn = 3e38f, sm = 0.f, sq = 0.f;
#pragma unroll
      for (int fr = 0; fr < 2; ++fr)
#pragma unroll
        for (int r = 0; r < 4; ++r) {
          float v = acc[fr][fc][r];
          mx = fmaxf(mx, v); mn = fminf(mn, v); sm += v; sq = fmaf(v, v, sq);
        }
#pragma unroll
      for (int off = 16; off <= 32; off <<= 1) {
        mx = fmaxf(mx, __shfl_xor(mx, off));
        mn = fminf(mn, __shfl_xor(mn, off));
        sm += __shfl_xor(sm, off);
        sq += __shfl_xor(sq, off);
      }
      if (lane < 16) {
        int col = fc * 16 + lr;
        smx[p][w][col] = mx; smn[p][w][col] = mn; ssm[p][w][col] = sm; ssq[p][w][col] = sq;
      }
    }
    __syncthreads();
    if (tid < CH) {
      float mx = smx[p][0][tid], mn = smn[p][0][tid], sm = ssm[p][0][tid], sq = ssq[p][0][tid];
#pragma unroll
      for (int w2 = 1; w2 < 4; ++w2) {
        mx = fmaxf(mx, smx[p][w2][tid]); mn = fminf(mn, smn[p][w2][tid]);
        sm += ssm[p][w2][tid]; sq += ssq[p][w2][tid];
      }
      z2mx[(size_t)f * CH + tid] = mx;
      z2mn[(size_t)f * CH + tid] = mn;
      psum[(size_t)f * CH + tid] = sm;
      psq[(size_t)f * CH + tid]  = sq;
    }
    cx0 = nx0; cx1 = nx1; cx2 = nx2; cx3 = nx3; cx4 = nx4; cx5 = nx5;
    mu4 = nmu; rs4 = nrs;
  }
}

// bn2 reduce, both stages (last-block pattern)
__global__ __launch_bounds__(256) void k_red(const float* __restrict__ psum, const float* __restrict__ psq,
    const float* __restrict__ w, const float* __restrict__ b, float* __restrict__ st,
    float* __restrict__ prs, float* __restrict__ prq, unsigned int* __restrict__ cnt,
    float invM, float eps) {
  __shared__ float s0[2][128], s1[2][128];
  __shared__ unsigned int lastv;
  int tid = threadIdx.x, c = tid & 127, half = tid >> 7;
  int f0 = blockIdx.x * 128;
  float sm = 0.f, sq = 0.f;
  for (int fl = half; fl < 128; fl += 2) {
    size_t idx = (size_t)(f0 + fl) * 128 + c;
    sm += psum[idx]; sq += psq[idx];
  }
  s0[half][c] = sm; s1[half][c] = sq;
  __syncthreads();
  if (tid < 128) {
    prs[blockIdx.x * 128 + tid] = s0[0][tid] + s0[1][tid];
    prq[blockIdx.x * 128 + tid] = s1[0][tid] + s1[1][tid];
  }
  __threadfence();
  __syncthreads();
  if (tid == 0) lastv = atomicAdd(cnt, 1u);
  __syncthreads();
  if (lastv != gridDim.x - 1) return;
  // last block: stage 2
  sm = 0.f; sq = 0.f;
  for (int g = half; g < 64; g += 2) { sm += prs[g * 128 + c]; sq += prq[g * 128 + c]; }
  __syncthreads();
  s0[half][c] = sm; s1[half][c] = sq;
  __syncthreads();
  if (tid < 128) {
    float tsm = s0[0][tid] + s0[1][tid], tsq = s1[0][tid] + s1[1][tid];
    float mean = tsm * invM;
    float var = tsq * invM - mean * mean;
    float s = w[tid] / sqrtf(var + eps);
    st[tid] = s;
    st[CH + tid] = b[tid] - mean * s;
  }
}

// fused feat + pre-LN + in-proj(layer0): h2(bf16) -> MFMA feat -> LDS LN -> as -> MFMA in-proj
__global__ __launch_bounds__(512) void k_fi(const float* __restrict__ z2mx, const float* __restrict__ z2mn,
    const float* __restrict__ s2t2, const u16* __restrict__ fprojB, const float* __restrict__ fpb,
    const float* __restrict__ plw, const float* __restrict__ plb,
    const u16* __restrict__ inwB_l, const float* __restrict__ inb,
    u16* __restrict__ gate, u16* __restrict__ upd) {
  __shared__ alignas(16) u16 h2s[32 * 128];
  __shared__ float ft[32 * 260];
  __shared__ alignas(16) u16 as[32 * 256];
  int f0 = blockIdx.x * 32, tid = threadIdx.x;
  int lane = tid & 63, w = tid >> 6, lr = lane & 15, kg = lane >> 4;
  {
    int row = tid >> 4, cc = tid & 15, c0 = cc * 8;
    const float* zx = z2mx + (size_t)(f0 + row) * 128 + c0;
    const float* zn = z2mn + (size_t)(f0 + row) * 128 + c0;
    bf16x8 v;
#pragma unroll
    for (int q = 0; q < 8; ++q) {
      int c = c0 + q;
      float s = s2t2[c], t = s2t2[128 + c];
      float z = (s >= 0.f) ? zx[q] : zn[q];
      v[q] = (short)f2bf(fmaxf(0.f, fmaf(s, z, t)));
    }
    *(bf16x8*)&h2s[row * 128 + ((cc ^ (row & 7)) << 3)] = v;
  }
  __syncthreads();
  {
    f32x4 fac[2][2];
#pragma unroll
    for (int fr = 0; fr < 2; ++fr)
#pragma unroll
      for (int fc = 0; fc < 2; ++fc) fac[fr][fc] = (f32x4){0.f, 0.f, 0.f, 0.f};
#pragma unroll
    for (int ks = 0; ks < 4; ++ks) {
      int kc = ks * 4 + kg;
      bf16x8 a0 = *(const bf16x8*)&h2s[lr * 128 + ((kc ^ (lr & 7)) << 3)];
      bf16x8 a1 = *(const bf16x8*)&h2s[(16 + lr) * 128 + ((kc ^ (lr & 7)) << 3)];
#pragma unroll
      for (int fc = 0; fc < 2; ++fc) {
        int d = w * 32 + fc * 16 + lr;
        bf16x8 b = *(const bf16x8*)&fprojB[(size_t)d * 128 + kc * 8];
        fac[0][fc] = MFMA16(a0, b, fac[0][fc], 0, 0, 0);
        fac[1][fc] = MFMA16(a1, b, fac[1][fc], 0, 0, 0);
      }
    }
#pragma unroll
    for (int fr = 0; fr < 2; ++fr)
#pragma unroll
      for (int fc = 0; fc < 2; ++fc) {
        int d = w * 32 + fc * 16 + lr;
        float bias = fpb[d];
#pragma unroll
        for (int r = 0; r < 4; ++r) {
          int row = fr * 16 + kg * 4 + r;
          ft[row * 260 + d] = fac[fr][fc][r] + bias;
        }
      }
  }
  __syncthreads();
  {
    float4 plw4 = ((const float4*)plw)[lane];
    float4 plb4 = ((const float4*)plb)[lane];
#pragma unroll
    for (int q = 0; q < 4; ++q) {
      int row = w * 4 + q;
      float4 v = *(const float4*)&ft[row * 260 + lane * 4];
      float s = v.x + v.y + v.z + v.w;
#pragma unroll
      for (int off = 32; off; off >>= 1) s += __shfl_xor(s, off);
      float mu = s * (1.f / 256.f);
      float4 dd = make_float4(v.x - mu, v.y - mu, v.z - mu, v.w - mu);
      float qq = dd.x*dd.x + dd.y*dd.y + dd.z*dd.z + dd.w*dd.w;
#pragma unroll
      for (int off = 32; off; off >>= 1) qq += __shfl_xor(qq, off);
      float rs = 1.f / sqrtf(qq * (1.f / 256.f) + 1e-5f);
      u16 o[4];
      o[0] = f2bf(fmaf(dd.x * rs, plw4.x, plb4.x));
      o[1] = f2bf(fmaf(dd.y * rs, plw4.y, plb4.y));
      o[2] = f2bf(fmaf(dd.z * rs, plw4.z, plb4.z));
      o[3] = f2bf(fmaf(dd.w * rs, plw4.w, plb4.w));
      int chunk = lane >> 1;
      *(uint2*)&as[row * 256 + ((chunk ^ (row & 7)) << 3) + (lane & 1) * 4] = *(uint2*)o;
    }
  }
  __syncthreads();
  f32x4 acc[2][8];
#pragma unroll
  for (int fr = 0; fr < 2; ++fr)
#pragma unroll
    for (int fc = 0; fc < 8; ++fc) acc[fr][fc] = (f32x4){0.f, 0.f, 0.f, 0.f};
  int colb = w * 128;
#pragma unroll
  for (int ks = 0; ks < 8; ++ks) {
    int kc = ks * 4 + kg;
    int r1 = 16 + lr;
    bf16x8 a0 = *(const bf16x8*)&as[lr * 256 + ((kc ^ (lr & 7)) << 3)];
    bf16x8 a1 = *(const bf16x8*)&as[r1 * 256 + ((kc ^ (r1 & 7)) << 3)];
#pragma unroll
    for (int fc = 0; fc < 8; ++fc) {
      int col = colb + fc * 16 + lr;
      bf16x8 b = *(const bf16x8*)&inwB_l[(size_t)col * 256 + kc * 8];
      acc[0][fc] = MFMA16(a0, b, acc[0][fc], 0, 0, 0);
      acc[1][fc] = MFMA16(a1, b, acc[1][fc], 0, 0, 0);
    }
  }
  bool isGate = (w < 4);
  u16* dst = isGate ? gate : upd;
  int cbOff = isGate ? 0 : 512;
#pragma unroll
  for (int fr = 0; fr < 2; ++fr)
#pragma unroll
    for (int fc = 0; fc < 8; ++fc) {
      int cg = colb + fc * 16 + lr;
      float bias = inb[cg];
      int colOut = cg - cbOff;
#pragma unroll
      for (int r = 0; r < 4; ++r) {
        int frame = f0 + fr * 16 + kg * 4 + r;
        float v = acc[fr][fc][r] + bias;
        float sg = sigmoidf_(v);
        v = isGate ? sg : v * sg;
        dst[(size_t)frame * 512 + colOut] = f2bf(v);
      }
    }
}

// Bu = conv(upd) @ Bm + cbB (masked); 32 frames/block, 4 waves: 2 frame-groups x 2 h-halves
__global__ __launch_bounds__(256) void k_bu(const u16* __restrict__ updB, const u16* __restrict__ BmTd_l,
    const float* __restrict__ cbB_l, const int* __restrict__ lengths, float* __restrict__ bu) {
  __shared__ float part[2][32][16];
  int tid = threadIdx.x, lane = tid & 63, w = tid >> 6;
  int wf = w & 1, hh = w >> 1;
  int f0 = blockIdx.x * 32 + wf * 16;
  int lr = lane & 15, kg = lane >> 4;
  int t = (f0 & 511) + lr;
  const u16* arow = updB + (size_t)(f0 + lr) * 512;
  bool v0 = (t >= 2), v1 = (t >= 1), v3 = (t <= 510);
  const bf16x8 zv = (bf16x8){0,0,0,0,0,0,0,0};
  f32x4 acc = (f32x4){0.f, 0.f, 0.f, 0.f};
#pragma unroll
  for (int ks = 0; ks < 8; ++ks) {
    int kc = hh * 32 + ks * 4 + kg, co = kc * 8;
    bf16x8 a0 = v0 ? *(const bf16x8*)&arow[co - 1024] : zv;
    bf16x8 a1 = v1 ? *(const bf16x8*)&arow[co - 512]  : zv;
    bf16x8 a2 =      *(const bf16x8*)&arow[co];
    bf16x8 a3 = v3 ? *(const bf16x8*)&arow[co + 512]  : zv;
    acc = MFMA16(a0, *(const bf16x8*)&BmTd_l[0 * 8192 + lr * 512 + co], acc, 0, 0, 0);
    acc = MFMA16(a1, *(const bf16x8*)&BmTd_l[1 * 8192 + lr * 512 + co], acc, 0, 0, 0);
    acc = MFMA16(a2, *(const bf16x8*)&BmTd_l[2 * 8192 + lr * 512 + co], acc, 0, 0, 0);
    acc = MFMA16(a3, *(const bf16x8*)&BmTd_l[3 * 8192 + lr * 512 + co], acc, 0, 0, 0);
  }
#pragma unroll
  for (int r = 0; r < 4; ++r) part[hh][wf * 16 + kg * 4 + r][lr] = acc[r];
  __syncthreads();
  int len = lengths[blockIdx.x >> 4];
  for (int i = tid; i < 512; i += 256) {
    int fl = i >> 4, s = i & 15;
    int frame = blockIdx.x * 32 + fl;
    int tt = frame & 511, bi = frame >> 9;
    float val = part[0][fl][s] + part[1][fl][s] + cbB_l[s];
    bu[((size_t)bi * 16 + s) * 512 + tt] = (tt < len) ? val : 0.f;
  }
}

// fused mamba-out(l) + mamba-in(l+1)
__global__ __launch_bounds__(512) void k_mo(const float* __restrict__ bu,
    u16* __restrict__ gateB, u16* __restrict__ updB,
    const u16* __restrict__ albB_l, const u16* __restrict__ outwB_l, const float* __restrict__ outb,
    const u16* __restrict__ inwB_n, const float* __restrict__ inb_n,
    const int* __restrict__ lengths) {
  __shared__ alignas(16) u16 hsb[32 * 40];
  __shared__ alignas(16) u16 vl[32 * 512];
  __shared__ alignas(16) u16 as[32 * 256];
  int f0 = blockIdx.x * 32, tid = threadIdx.x;
  int bb = f0 >> 9, tbase = f0 & 511;
  int len = lengths[bb];
  int lane = tid & 63, w = tid >> 6, lr = lane & 15, kg = lane >> 4;
  for (int i = tid; i < 640; i += 512) ((unsigned int*)hsb)[i] = 0;
  __syncthreads();
#pragma unroll
  for (int q = 0; q < 2; ++q) {
    int s = w * 2 + q;
    const float* src = bu + ((size_t)bb * 16 + s) * 512 + lane * 8;
    float4 v0 = *(const float4*)src, v1 = *(const float4*)(src + 4);
    float p0 = v0.x, p1 = p0 + v0.y, p2 = p1 + v0.z, p3 = p2 + v0.w;
    float p4 = p3 + v1.x, p5 = p4 + v1.y, p6 = p5 + v1.z, p7 = p6 + v1.w;
    float tot = p7;
#pragma unroll
    for (int off = 1; off < 64; off <<= 1) {
      float n = __shfl_up(tot, off);
      if (lane >= off) tot += n;
    }
    float excl = tot - p7;
    int rbase = lane * 8 - tbase;
    if (rbase >= 0 && rbase < 32) {
      hsb[(rbase + 0) * 40 + s] = f2bf(p0 + excl);
      hsb[(rbase + 1) * 40 + s] = f2bf(p1 + excl);
      hsb[(rbase + 2) * 40 + s] = f2bf(p2 + excl);
      hsb[(rbase + 3) * 40 + s] = f2bf(p3 + excl);
      hsb[(rbase + 4) * 40 + s] = f2bf(p4 + excl);
      hsb[(rbase + 5) * 40 + s] = f2bf(p5 + excl);
      hsb[(rbase + 6) * 40 + s] = f2bf(p6 + excl);
      hsb[(rbase + 7) * 40 + s] = f2bf(p7 + excl);
    }
  }
  __syncthreads();
  {
    bf16x8 a0 = *(const bf16x8*)&hsb[lr * 40 + kg * 8];
    bf16x8 a1 = *(const bf16x8*)&hsb[(16 + lr) * 40 + kg * 8];
    f32x4 zero = (f32x4){0.f, 0.f, 0.f, 0.f};
#pragma unroll
    for (int fc = 0; fc < 4; ++fc) {
      int h = w * 64 + fc * 16 + lr;
      bf16x8 b = *(const bf16x8*)&albB_l[h * 32 + kg * 8];
      f32x4 va = MFMA16(a0, b, zero, 0, 0, 0);
      f32x4 vb = MFMA16(a1, b, zero, 0, 0, 0);
      int hck = h >> 3, hlo = h & 7;
#pragma unroll
      for (int fr = 0; fr < 2; ++fr) {
        f32x4 vv = fr ? vb : va;
#pragma unroll
        for (int r = 0; r < 4; ++r) {
          int fl = fr * 16 + kg * 4 + r;
          int frame = f0 + fl;
          float g = bf2f(gateB[(size_t)frame * 512 + h]);
          float val = ((frame & 511) < len) ? vv[r] * g : 0.f;
          vl[fl * 512 + ((hck ^ (fl & 7)) << 3) + hlo] = f2bf(val);
        }
      }
    }
  }
  __syncthreads();
  {
    f32x4 acc2[2][2];
#pragma unroll
    for (int fr = 0; fr < 2; ++fr)
#pragma unroll
      for (int fc = 0; fc < 2; ++fc) acc2[fr][fc] = (f32x4){0.f, 0.f, 0.f, 0.f};
    int db = w * 32;
#pragma unroll
    for (int ks = 0; ks < 16; ++ks) {
      int kc = ks * 4 + kg;
      int r1 = 16 + lr;
      bf16x8 a0 = *(const bf16x8*)&vl[lr * 512 + ((kc ^ (lr & 7)) << 3)];
      bf16x8 a1 = *(const bf16x8*)&vl[r1 * 512 + ((kc ^ (r1 & 7)) << 3)];
#pragma unroll
      for (int fc = 0; fc < 2; ++fc) {
        int d = db + fc * 16 + lr;
        bf16x8 b = *(const bf16x8*)&outwB_l[(size_t)d * 512 + kc * 8];
        acc2[0][fc] = MFMA16(a0, b, acc2[0][fc], 0, 0, 0);
        acc2[1][fc] = MFMA16(a1, b, acc2[1][fc], 0, 0, 0);
      }
    }
#pragma unroll
    for (int fr = 0; fr < 2; ++fr)
#pragma unroll
      for (int fc = 0; fc < 2; ++fc) {
        int d = db + fc * 16 + lr;
        float bias = outb[d];
        int dck = d >> 3, dlo = d & 7;
#pragma unroll
        for (int r = 0; r < 4; ++r) {
          int row = fr * 16 + kg * 4 + r;
          as[row * 256 + ((dck ^ (row & 7)) << 3) + dlo] = f2bf(acc2[fr][fc][r] + bias);
        }
      }
  }
  __syncthreads();
  f32x4 acc[2][8];
#pragma unroll
  for (int fr = 0; fr < 2; ++fr)
#pragma unroll
    for (int fc = 0; fc < 8; ++fc) acc[fr][fc] = (f32x4){0.f, 0.f, 0.f, 0.f};
  int colb = w * 128;
#pragma unroll
  for (int ks = 0; ks < 8; ++ks) {
    int kc = ks * 4 + kg;
    int r1 = 16 + lr;
    bf16x8 a0 = *(const bf16x8*)&as[lr * 256 + ((kc ^ (lr & 7)) << 3)];
    bf16x8 a1 = *(const bf16x8*)&as[r1 * 256 + ((kc ^ (r1 & 7)) << 3)];
#pragma unroll
    for (int fc = 0; fc < 8; ++fc) {
      int col = colb + fc * 16 + lr;
      bf16x8 b = *(const bf16x8*)&inwB_n[(size_t)col * 256 + kc * 8];
      acc[0][fc] = MFMA16(a0, b, acc[0][fc], 0, 0, 0);
      acc[1][fc] = MFMA16(a1, b, acc[1][fc], 0, 0, 0);
    }
  }
  bool isGate = (w < 4);
  u16* dst = isGate ? gateB : updB;
  int cbOff = isGate ? 0 : 512;
#pragma unroll
  for (int fr = 0; fr < 2; ++fr)
#pragma unroll
    for (int fc = 0; fc < 8; ++fc) {
      int cg = colb + fc * 16 + lr;
      float bias = inb_n[cg];
      int colOut = cg - cbOff;
#pragma unroll
      for (int r = 0; r < 4; ++r) {
        int frame = f0 + fr * 16 + kg * 4 + r;
        float v = acc[fr][fc][r] + bias;
        float sg = sigmoidf_(v);
        v = isGate ? sg : v * sg;
        dst[(size_t)frame * 512 + colOut] = f2bf(v);
      }
    }
}

// final-layer out-proj (standalone, with fused scan prologue) -> sout f32
__global__ __launch_bounds__(256) void k_out(const float* __restrict__ bu, const u16* __restrict__ gateB,
    const u16* __restrict__ albB_l, const u16* __restrict__ outwB_l, const float* __restrict__ outb,
    const int* __restrict__ lengths, float* __restrict__ sout) {
  __shared__ alignas(16) u16 hsb[32 * 40];
  __shared__ alignas(16) u16 vl[32 * 512];
  int f0 = blockIdx.x * 32, tid = threadIdx.x;
  int bb = f0 >> 9, tbase = f0 & 511;
  int len = lengths[bb];
  int lane = tid & 63, w = tid >> 6, lr = lane & 15, kg = lane >> 4;
  for (int i = tid; i < 640; i += 256) ((unsigned int*)hsb)[i] = 0;
  __syncthreads();
#pragma unroll
  for (int q = 0; q < 4; ++q) {
    int s = w * 4 + q;
    const float* src = bu + ((size_t)bb * 16 + s) * 512 + lane * 8;
    float4 v0 = *(const float4*)src, v1 = *(const float4*)(src + 4);
    float p0 = v0.x, p1 = p0 + v0.y, p2 = p1 + v0.z, p3 = p2 + v0.w;
    float p4 = p3 + v1.x, p5 = p4 + v1.y, p6 = p5 + v1.z, p7 = p6 + v1.w;
    float tot = p7;
#pragma unroll
    for (int off = 1; off < 64; off <<= 1) {
      float n = __shfl_up(tot, off);
      if (lane >= off) tot += n;
    }
    float excl = tot - p7;
    int rbase = lane * 8 - tbase;
    if (rbase >= 0 && rbase < 32) {
      hsb[(rbase + 0) * 40 + s] = f2bf(p0 + excl);
      hsb[(rbase + 1) * 40 + s] = f2bf(p1 + excl);
      hsb[(rbase + 2) * 40 + s] = f2bf(p2 + excl);
      hsb[(rbase + 3) * 40 + s] = f2bf(p3 + excl);
      hsb[(rbase + 4) * 40 + s] = f2bf(p4 + excl);
      hsb[(rbase + 5) * 40 + s] = f2bf(p5 + excl);
      hsb[(rbase + 6) * 40 + s] = f2bf(p6 + excl);
      hsb[(rbase + 7) * 40 + s] = f2bf(p7 + excl);
    }
  }
  __syncthreads();
  {
    bf16x8 a0 = *(const bf16x8*)&hsb[lr * 40 + kg * 8];
    bf16x8 a1 = *(const bf16x8*)&hsb[(16 + lr) * 40 + kg * 8];
    f32x4 zero = (f32x4){0.f, 0.f, 0.f, 0.f};
#pragma unroll
    for (int fc = 0; fc < 8; ++fc) {
      int h = w * 128 + fc * 16 + lr;
      bf16x8 b = *(const bf16x8*)&albB_l[h * 32 + kg * 8];
      f32x4 va = MFMA16(a0, b, zero, 0, 0, 0);
      f32x4 vb = MFMA16(a1, b, zero, 0, 0, 0);
      int hck = h >> 3, hlo = h & 7;
#pragma unroll
      for (int fr = 0; fr < 2; ++fr) {
        f32x4 vv = fr ? vb : va;
#pragma unroll
        for (int r = 0; r < 4; ++r) {
          int fl = fr * 16 + kg * 4 + r;
          int frame = f0 + fl;
          float g = bf2f(gateB[(size_t)frame * 512 + h]);
          float val = ((frame & 511) < len) ? vv[r] * g : 0.f;
          vl[fl * 512 + ((hck ^ (fl & 7)) << 3) + hlo] = f2bf(val);
        }
      }
    }
  }
  __syncthreads();
  f32x4 acc[2][4];
#pragma unroll
  for (int fr = 0; fr < 2; ++fr)
#pragma unroll
    for (int fc = 0; fc < 4; ++fc) acc[fr][fc] = (f32x4){0.f, 0.f, 0.f, 0.f};
  int db = w * 64;
#pragma unroll
  for (int ks = 0; ks < 16; ++ks) {
    int kc = ks * 4 + kg;
    int r1 = 16 + lr;
    bf16x8 a0 = *(const bf16x8*)&vl[lr * 512 + ((kc ^ (lr & 7)) << 3)];
    bf16x8 a1 = *(const bf16x8*)&vl[r1 * 512 + ((kc ^ (r1 & 7)) << 3)];
#pragma unroll
    for (int fc = 0; fc < 4; ++fc) {
      int d = db + fc * 16 + lr;
      bf16x8 b = *(const bf16x8*)&outwB_l[(size_t)d * 512 + kc * 8];
      acc[0][fc] = MFMA16(a0, b, acc[0][fc], 0, 0, 0);
      acc[1][fc] = MFMA16(a1, b, acc[1][fc], 0, 0, 0);
    }
  }
#pragma unroll
  for (int fr = 0; fr < 2; ++fr)
#pragma unroll
    for (int fc = 0; fc < 4; ++fc) {
      int d = db + fc * 16 + lr;
      float bias = outb[d];
#pragma unroll
      for (int r = 0; r < 4; ++r) {
        int frame = f0 + fr * 16 + kg * 4 + r;
        sout[(size_t)frame * 256 + d] = acc[fr][fc][r] + bias;
      }
    }
}

// post-LN + masked pool stage 1: grid 128 (16 b x 8 chunks of 64 frames) -> partial sums
__global__ __launch_bounds__(512) void k_pp1(const float* __restrict__ seq, const int* __restrict__ lengths,
    const float* __restrict__ w, const float* __restrict__ b, float* __restrict__ ppart) {
  __shared__ float4 part[8][64];
  int bb = blockIdx.x >> 3, ck = blockIdx.x & 7;
  int tid = threadIdx.x, lane = tid & 63, wv = tid >> 6;
  int len = lengths[bb];
  float4 w4 = ((const float4*)w)[lane], b4 = ((const float4*)b)[lane];
  float4 pacc = make_float4(0.f, 0.f, 0.f, 0.f);
#pragma unroll
  for (int it = 0; it < 8; ++it) {
    int t = ck * 64 + it * 8 + wv;
    float4 v = ((const float4*)(seq + ((size_t)bb * 512 + t) * DD))[lane];
    float s = v.x + v.y + v.z + v.w;
#pragma unroll
    for (int off = 32; off; off >>= 1) s += __shfl_xor(s, off);
    float mu = s * (1.f / 256.f);
    float4 dd = make_float4(v.x - mu, v.y - mu, v.z - mu, v.w - mu);
    float q = dd.x*dd.x + dd.y*dd.y + dd.z*dd.z + dd.w*dd.w;
#pragma unroll
    for (int off = 32; off; off >>= 1) q += __shfl_xor(q, off);
    float rs = 1.f / sqrtf(q * (1.f / 256.f) + 1e-5f);
    if (t < len) {
      pacc.x += fmaf(dd.x * rs, w4.x, b4.x);
      pacc.y += fmaf(dd.y * rs, w4.y, b4.y);
      pacc.z += fmaf(dd.z * rs, w4.z, b4.z);
      pacc.w += fmaf(dd.w * rs, w4.w, b4.w);
    }
  }
  part[wv][lane] = pacc;
  __syncthreads();
  if (tid < 64) {
    float4 a = part[0][tid];
#pragma unroll
    for (int w2 = 1; w2 < 8; ++w2) {
      float4 p = part[w2][tid];
      a.x += p.x; a.y += p.y; a.z += p.z; a.w += p.w;
    }
    ((float4*)(ppart + (size_t)blockIdx.x * DD))[tid] = a;
  }
}

// wave-per-output MLP; mode=1: build lin from 8 chunk partials / len (fused old k_pp2)
__global__ __launch_bounds__(256) void k_mlp(const float* __restrict__ in, const float* __restrict__ W,
    const float* __restrict__ bias, float* __restrict__ out, int K, int Nout, int act,
    const int* __restrict__ lengths, int mode) {
  __shared__ float lin[16 * 1024];
  int tid = threadIdx.x, lane = tid & 63, w = tid >> 6;
  if (mode) {
    for (int i = tid; i < 16 * 256; i += 256) {
      int r = i >> 8, c2 = i & 255;
      float a = 0.f;
#pragma unroll
      for (int ck = 0; ck < 8; ++ck) a += in[(size_t)((r << 3) + ck) * 256 + c2];
      lin[r * 256 + c2] = a / (float)max(lengths[r], 1);
    }
  } else {
    for (int i = tid; i < 16 * K / 4; i += 256) ((float4*)lin)[i] = ((const float4*)in)[i];
  }
  __syncthreads();
  int o = blockIdx.x * 4 + w;
  const float4* wr4 = (const float4*)(W + (size_t)o * K);
  float acc[16];
#pragma unroll
  for (int r = 0; r < 16; ++r) acc[r] = 0.f;
  for (int k4 = lane; k4 < K / 4; k4 += 64) {
    float4 wv = wr4[k4];
    int kb = k4 * 4;
#pragma unroll
    for (int r = 0; r < 16; ++r) {
      float4 lv = *(const float4*)&lin[r * K + kb];
      acc[r] = fmaf(lv.x, wv.x, fmaf(lv.y, wv.y, fmaf(lv.z, wv.z, fmaf(lv.w, wv.w, acc[r]))));
    }
  }
#pragma unroll
  for (int r = 0; r < 16; ++r) {
#pragma unroll
    for (int off = 32; off; off >>= 1) acc[r] += __shfl_xor(acc[r], off);
  }
  if (lane < 16) {
    float v = 0.f;
#pragma unroll
    for (int r = 0; r < 16; ++r) if (lane == r) v = acc[r];
    v += bias[o];
    if (act) v = geluf_(v);
    out[(size_t)lane * Nout + o] = v;
  }
}

// L2 normalize rows of e[16][512]
__global__ __launch_bounds__(256) void k_norm(const float* __restrict__ e, float* __restrict__ out) {
  __shared__ float sc[4];
  int b = blockIdx.x, tid = threadIdx.x;
  float v0 = e[(size_t)b * 512 + tid], v1 = e[(size_t)b * 512 + 256 + tid];
  float ss = red256(v0 * v0 + v1 * v1, tid, sc);
  float nrm = fmaxf(sqrtf(ss), 1e-12f);
  out[(size_t)b * 512 + tid] = v0 / nrm;
  out[(size_t)b * 512 + 256 + tid] = v1 / nrm;
}

// ---------------- launch ----------------

extern "C" void kernel_launch(void* const* d_in, const int* in_sizes, int n_in,
                              void* d_out, int out_size, void* d_ws, size_t ws_size,
                              hipStream_t stream) {
  const float* x         = (const float*)d_in[0];
  const int*   lengths   = (const int*)d_in[1];
  const float* conv1_w   = (const float*)d_in[2];
  const float* bn1_w     = (const float*)d_in[3];
  const float* bn1_b     = (const float*)d_in[4];
  const float* conv2_w   = (const float*)d_in[5];
  const float* bn2_w     = (const float*)d_in[6];
  const float* bn2_b     = (const float*)d_in[7];
  const float* fproj_w   = (const float*)d_in[8];
  const float* fproj_b   = (const float*)d_in[9];
  const float* pre_ln_w  = (const float*)d_in[10];
  const float* pre_ln_b  = (const float*)d_in[11];
  const float* in_w      = (const float*)d_in[12];
  const float* in_b      = (const float*)d_in[13];
  const float* conv_w    = (const float*)d_in[14];
  const float* conv_b    = (const float*)d_in[15];
  const float* A         = (const float*)d_in[16];
  const float* Bm        = (const float*)d_in[17];
  const float* out_w     = (const float*)d_in[18];
  const float* out_b     = (const float*)d_in[19];
  const float* post_ln_w = (const float*)d_in[20];
  const float* post_ln_b = (const float*)d_in[21];
  const float* m1_w      = (const float*)d_in[22];
  const float* m1_b      = (const float*)d_in[23];
  const float* m2_w      = (const float*)d_in[24];
  const float* m2_b      = (const float*)d_in[25];
  const float* m3_w      = (const float*)d_in[26];
  const float* m3_b      = (const float*)d_in[27];
  float* outp = (float*)d_out;

  float* wsf = (float*)d_ws;
  size_t o = 0;
  auto F32 = [&](size_t n) { float* p = wsf + o; o += (n + 63) & ~(size_t)63; return p; };
  float* psum   = F32(1048576);
  float* psq    = F32(1048576);
  float* z2mx   = F32(1048576);
  float* z2mn   = F32(1048576);
  float* msd    = F32(65536);
  float* pstat  = F32(16384);
  float* cc     = F32(512);
  float* s2t2   = F32(256);
  float* prs    = F32(8192);
  float* prq    = F32(8192);
  float* cnts   = F32(64);              // [0]=k_mom ticket, [1]=k_red ticket
  u16*   W2B    = (u16*)F32(8192);      // 16384 bf16
  u16*   fprojB = (u16*)F32(16384);     // 32768 bf16
  u16*   inwB   = (u16*)F32(524288);    // 1048576 bf16
  u16*   outwB  = (u16*)F32(262144);    // 524288 bf16
  u16*   albB   = (u16*)F32(32768);     // 65536 bf16
  u16*   BmTd   = (u16*)F32(65536);     // 131072 bf16
  float* cbB    = F32(64);
  float* seqA   = F32(2097152);
  u16*   gateB  = (u16*)F32(2097152);   // 8192x512 bf16
  u16*   updB   = (u16*)F32(2097152);
  float* buv    = F32(131072);
  float* ppart  = F32(32768);
  float* e1     = F32(16384);
  float* e2     = F32(16384);
  float* e3     = F32(8192);
  if (ws_size < o * sizeof(float)) return;

  const float invM = 1.f / (float)(NFRM * NPT);

  hipMemsetAsync(cnts, 0, 8, stream);   // zero both last-block tickets (deterministic)
  k_prep<<<2416, 256, 0, stream>>>(conv2_w, fproj_w, in_w, out_w, A, Bm, conv_w, conv_b,
                                   W2B, fprojB, inwB, outwB, albB, BmTd, cbB);
  k_mom<<<2048, 256, 0, stream>>>(x, msd, pstat, conv1_w, bn1_w, bn1_b, cc,
                                  (unsigned int*)cnts);
  k2_main<<<NFRM / 4, 256, 0, stream>>>(x, (const float4*)cc, (const float4*)msd, W2B,
                                        z2mx, z2mn, psum, psq);
  k_red<<<64, 256, 0, stream>>>(psum, psq, bn2_w, bn2_b, s2t2, prs, prq,
                                (unsigned int*)cnts + 1, invM, 1e-5f);
  k_fi<<<NFRM / 32, 512, 0, stream>>>(z2mx, z2mn, s2t2, fprojB, fproj_b, pre_ln_w, pre_ln_b,
                                      inwB, in_b, gateB, updB);

  for (int l = 0; l < 3; ++l) {
    k_bu<<<NFRM / 32, 256, 0, stream>>>(updB, BmTd + (size_t)l * 32768, cbB + l * 16, lengths, buv);
    k_mo<<<NFRM / 32, 512, 0, stream>>>(buv, gateB, updB,
                                        albB + (size_t)l * 16384, outwB + (size_t)l * 131072,
                                        out_b + l * 256,
                                        inwB + (size_t)(l + 1) * 262144, in_b + (l + 1) * 1024,
                                        lengths);
  }
  k_bu<<<NFRM / 32, 256, 0, stream>>>(updB, BmTd + (size_t)3 * 32768, cbB + 3 * 16, lengths, buv);
  k_out<<<NFRM / 32, 256, 0, stream>>>(buv, gateB, albB + (size_t)3 * 16384,
                                       outwB + (size_t)3 * 131072, out_b + 3 * 256, lengths, seqA);
  k_pp1<<<128, 512, 0, stream>>>(seqA, lengths, post_ln_w, post_ln_b, ppart);
  k_mlp<<<256, 256, 0, stream>>>(ppart, m1_w, m1_b, e1, 256, 1024, 1, lengths, 1);
  k_mlp<<<256, 256, 0, stream>>>(e1, m2_w, m2_b, e2, 1024, 1024, 1, lengths, 0);
  k_mlp<<<128, 256, 0, stream>>>(e2, m3_w, m3_b, e3, 1024, 512, 0, lengths, 0);
  k_norm<<<16, 256, 0, stream>>>(e3, outp);
}

// Round 14
// 369.533 us; speedup vs baseline: 1.4147x; 1.4147x over previous
//
#include <hip/hip_runtime.h>
#include <hip/hip_bf16.h>
#include <math.h>

#define NFRM 8192   // B*T
#define NPT  128    // N points
#define CH   128    // HID
#define DD   256    // D
#define HH   512    // H
#define SS   16     // S
#define NL   4

typedef __attribute__((ext_vector_type(8))) short bf16x8;
typedef __attribute__((ext_vector_type(4))) float f32x4;
typedef unsigned short u16;

#define MFMA16 __builtin_amdgcn_mfma_f32_16x16x32_bf16

// ---------------- helpers ----------------

__device__ __forceinline__ float red256(float v, int tid, volatile float* sc) {
#pragma unroll
  for (int off = 32; off; off >>= 1) v += __shfl_down(v, off);
  __syncthreads();
  if ((tid & 63) == 0) sc[tid >> 6] = v;
  __syncthreads();
  return sc[0] + sc[1] + sc[2] + sc[3];
}

__device__ __forceinline__ float sigmoidf_(float x) { return 1.f / (1.f + __expf(-x)); }
__device__ __forceinline__ float geluf_(float x) { return 0.5f * x * (1.f + erff(x * 0.70710678118654752f)); }

__device__ __forceinline__ u16 f2bf(float f) {
  __hip_bfloat16 h = __float2bfloat16(f);
  return *(u16*)&h;
}
__device__ __forceinline__ float bf2f(u16 u) {
  union { unsigned int i; float f; } v; v.i = ((unsigned int)u) << 16; return v.f;
}

// ---------------- kernels ----------------

// pack weights (vectorized casts). BmTd[l][d][s][h] = cw[l][h][d]*Bm[l][h][s]; cbB[l][s] = sum_h cb*Bm
__global__ __launch_bounds__(256) void k_prep(const float* __restrict__ conv2_w,
    const float* __restrict__ fproj_w, const float* __restrict__ in_w, const float* __restrict__ out_w,
    const float* __restrict__ A, const float* __restrict__ Bm,
    const float* __restrict__ cw, const float* __restrict__ cb,
    u16* __restrict__ W2B, u16* __restrict__ fprojB, u16* __restrict__ inwB,
    u16* __restrict__ outwB, u16* __restrict__ albB, u16* __restrict__ BmTd,
    float* __restrict__ cbB) {
  int idx = blockIdx.x * 256 + threadIdx.x;
  if (idx < 16384) {
    int c = idx >> 7, k = idx & 127;
    int dst = c * 128 + ((((k >> 3) ^ (c & 7)) << 3) | (k & 7));
    W2B[dst] = f2bf(conv2_w[idx]);
    return;
  }
  idx -= 16384;
  if (idx < 8192) {            // fprojB
    float4 v = ((const float4*)fproj_w)[idx];
    ushort4 o; o.x = f2bf(v.x); o.y = f2bf(v.y); o.z = f2bf(v.z); o.w = f2bf(v.w);
    ((ushort4*)fprojB)[idx] = o;
    return;
  }
  idx -= 8192;
  if (idx < 262144) {          // inwB
    float4 v = ((const float4*)in_w)[idx];
    ushort4 o; o.x = f2bf(v.x); o.y = f2bf(v.y); o.z = f2bf(v.z); o.w = f2bf(v.w);
    ((ushort4*)inwB)[idx] = o;
    return;
  }
  idx -= 262144;
  if (idx < 131072) {          // outwB
    float4 v = ((const float4*)out_w)[idx];
    ushort4 o; o.x = f2bf(v.x); o.y = f2bf(v.y); o.z = f2bf(v.z); o.w = f2bf(v.w);
    ((ushort4*)outwB)[idx] = o;
    return;
  }
  idx -= 131072;
  if (idx < 65536) {
    int l = idx >> 14, rem = idx & 16383, h = rem >> 5, kk = rem & 31;
    albB[idx] = (kk < 16) ? f2bf(A[(size_t)l * 8192 + h * 16 + kk]) : (u16)0;
    return;
  }
  idx -= 65536;
  if (idx < 131072) {
    int l = idx >> 15, rem = idx & 32767;
    int d = rem >> 13, rem2 = rem & 8191, s = rem2 >> 9, h = rem2 & 511;
    BmTd[idx] = f2bf(cw[(size_t)l * 2048 + h * 4 + d] * Bm[(size_t)l * 8192 + h * 16 + s]);
    return;
  }
  idx -= 131072;
  if (idx < 4096) {           // one wave per (l,s)
    int wsl = idx >> 6, lane = idx & 63;
    int l = wsl >> 4, s = wsl & 15;
    float acc = 0.f;
    for (int h = lane; h < 512; h += 64)
      acc = fmaf(cb[l * 512 + h], Bm[(size_t)l * 8192 + h * 16 + s], acc);
#pragma unroll
    for (int off = 32; off; off >>= 1) acc += __shfl_down(acc, off);
    if (lane == 0) cbB[wsl] = acc;
  }
}

// per-frame moments + per-block partial stats
__global__ __launch_bounds__(256) void k_mom(const float* __restrict__ x, float* __restrict__ msd,
                                             float* __restrict__ pstat) {
  __shared__ float mpart[4][6];
  int tid = threadIdx.x, lane = tid & 63, w = tid >> 6;
  int f = blockIdx.x * 4 + w;
  const float* xf = x + (size_t)f * 384 + lane * 6;
  float a0 = xf[0], a1 = xf[1], a2 = xf[2], b0 = xf[3], b1 = xf[4], b2 = xf[5];
  float s0 = a0 + b0, s1 = a1 + b1, s2 = a2 + b2;
  float p00 = a0*a0 + b0*b0, p01 = a0*a1 + b0*b1, p02 = a0*a2 + b0*b2;
  float p11 = a1*a1 + b1*b1, p12 = a1*a2 + b1*b2, p22 = a2*a2 + b2*b2;
#pragma unroll
  for (int off = 32; off; off >>= 1) {
    s0 += __shfl_down(s0, off); s1 += __shfl_down(s1, off); s2 += __shfl_down(s2, off);
    p00 += __shfl_down(p00, off); p01 += __shfl_down(p01, off); p02 += __shfl_down(p02, off);
    p11 += __shfl_down(p11, off); p12 += __shfl_down(p12, off); p22 += __shfl_down(p22, off);
  }
  if (lane == 0) {
    float mu0 = s0 * (1.f/128.f), mu1 = s1 * (1.f/128.f), mu2 = s2 * (1.f/128.f);
    float C00 = p00 - 128.f*mu0*mu0, C01 = p01 - 128.f*mu0*mu1, C02 = p02 - 128.f*mu0*mu2;
    float C11 = p11 - 128.f*mu1*mu1, C12 = p12 - 128.f*mu1*mu2, C22 = p22 - 128.f*mu2*mu2;
    float sd0 = sqrtf(C00 * (1.f/127.f)) + 1e-10f;
    float sd1 = sqrtf(C11 * (1.f/127.f)) + 1e-10f;
    float sd2 = sqrtf(C22 * (1.f/127.f)) + 1e-10f;
    mpart[w][0] = C00/(sd0*sd0); mpart[w][1] = C01/(sd0*sd1); mpart[w][2] = C02/(sd0*sd2);
    mpart[w][3] = C11/(sd1*sd1); mpart[w][4] = C12/(sd1*sd2); mpart[w][5] = C22/(sd2*sd2);
    float* d = msd + (size_t)f * 8;
    d[0] = mu0; d[1] = mu1; d[2] = mu2; d[3] = 0.f;
    d[4] = 1.f/sd0; d[5] = 1.f/sd1; d[6] = 1.f/sd2; d[7] = 0.f;
  }
  __syncthreads();
  if (tid < 8) {
    float tot = 0.f;
    if (tid < 6) { for (int w2 = 0; w2 < 4; ++w2) tot += mpart[w2][tid]; }
    pstat[blockIdx.x * 8 + tid] = tot;
  }
}

// final bn1 folded channel constants cc[c] = (s*w0, s*w1, s*w2, t)
__global__ __launch_bounds__(256) void k_stats2(const float* __restrict__ pstat, const float* __restrict__ w1,
    const float* __restrict__ bw, const float* __restrict__ bb, float* __restrict__ cc) {
  __shared__ float part[32][8];
  __shared__ float Mt[8];
  int tid = threadIdx.x, j = tid & 7, g = tid >> 3;
  float sm = 0.f;
  for (int r = g; r < 2048; r += 32) sm += pstat[r * 8 + j];
  part[g][j] = sm;
  __syncthreads();
  if (tid < 8) { float tot = 0.f; for (int g2 = 0; g2 < 32; ++g2) tot += part[g2][tid]; Mt[tid] = tot; }
  __syncthreads();
  if (tid < 128) {
    float w0 = w1[tid*3], wa = w1[tid*3+1], wb = w1[tid*3+2];
    float var = (w0*w0*Mt[0] + wa*wa*Mt[3] + wb*wb*Mt[5]
               + 2.f*(w0*wa*Mt[1] + w0*wb*Mt[2] + wa*wb*Mt[4])) * (1.f/1048576.f);
    float s = bw[tid] / sqrtf(var + 1e-5f);
    ((float4*)cc)[tid] = make_float4(s*w0, s*wa, s*wb, bb[tid]);
  }
}

// main fused kernel: 4 frames/block; parity stats LDS (1 barrier/frame); x prefetch
__global__ __launch_bounds__(256) void k2_main(const float* __restrict__ x, const float4* __restrict__ cc,
    const float4* __restrict__ msd4, const u16* __restrict__ W2B,
    float* __restrict__ z2mx, float* __restrict__ z2mn,
    float* __restrict__ psum, float* __restrict__ psq) {
  __shared__ alignas(16) u16 w2s[16384];     // 32KB, pre-swizzled
  __shared__ float4 ccs[144];                // stride-9 pad
  __shared__ float smx[2][4][CH], smn[2][4][CH], ssm[2][4][CH], ssq[2][4][CH];
  int tid = threadIdx.x;
  for (int i = tid; i < 2048; i += 256) ((float4*)w2s)[i] = ((const float4*)W2B)[i];
  if (tid < 128) ccs[tid + (tid >> 3)] = cc[tid];
  int lane = tid & 63, w = tid >> 6;
  int lr = lane & 15, kg = lane >> 4;
  int row0 = w * 32 + lr, row1 = row0 + 16;
  int f0i = blockIdx.x * 4;
  float4 mu4 = msd4[f0i * 2], rs4 = msd4[f0i * 2 + 1];
  const float* xr0 = x + (size_t)f0i * 384 + row0 * 3;
  const float* xr1 = x + (size_t)f0i * 384 + row1 * 3;
  float cx0 = xr0[0], cx1 = xr0[1], cx2 = xr0[2];
  float cx3 = xr1[0], cx4 = xr1[1], cx5 = xr1[2];
  __syncthreads();
  for (int fi = 0; fi < 4; ++fi) {
    int f = blockIdx.x * 4 + fi;
    int p = fi & 1;
    float xa0 = (cx0 - mu4.x) * rs4.x, xa1 = (cx1 - mu4.y) * rs4.y, xa2 = (cx2 - mu4.z) * rs4.z;
    float xb0 = (cx3 - mu4.x) * rs4.x, xb1 = (cx4 - mu4.y) * rs4.y, xb2 = (cx5 - mu4.z) * rs4.z;
    int fn = (f + 1 < NFRM) ? f + 1 : f;
    float4 nmu = msd4[fn * 2], nrs = msd4[fn * 2 + 1];
    const float* nr0 = x + (size_t)fn * 384 + row0 * 3;
    const float* nr1 = x + (size_t)fn * 384 + row1 * 3;
    float nx0 = nr0[0], nx1 = nr0[1], nx2 = nr0[2];
    float nx3 = nr1[0], nx4 = nr1[1], nx5 = nr1[2];
    f32x4 acc[2][8];
#pragma unroll
    for (int fr = 0; fr < 2; ++fr)
#pragma unroll
      for (int fc = 0; fc < 8; ++fc) acc[fr][fc] = (f32x4){0.f, 0.f, 0.f, 0.f};
#pragma unroll
    for (int ks = 0; ks < 4; ++ks) {
      int kc = ks * 4 + kg;
      int base9 = kc * 9;
      bf16x8 a0, a1;
#pragma unroll
      for (int q = 0; q < 8; ++q) {
        float4 c4 = ccs[base9 + q];
        float h0 = fmaxf(0.f, fmaf(xa0, c4.x, fmaf(xa1, c4.y, fmaf(xa2, c4.z, c4.w))));
        float h1 = fmaxf(0.f, fmaf(xb0, c4.x, fmaf(xb1, c4.y, fmaf(xb2, c4.z, c4.w))));
        a0[q] = (short)f2bf(h0); a1[q] = (short)f2bf(h1);
      }
#pragma unroll
      for (int fc = 0; fc < 8; ++fc) {
        int col = fc * 16 + lr;
        bf16x8 b = *(const bf16x8*)&w2s[col * 128 + ((kc ^ (col & 7)) << 3)];
        acc[0][fc] = MFMA16(a0, b, acc[0][fc], 0, 0, 0);
        acc[1][fc] = MFMA16(a1, b, acc[1][fc], 0, 0, 0);
      }
    }
#pragma unroll
    for (int fc = 0; fc < 8; ++fc) {
      float mx = -3e38f, mn = 3e38f, sm = 0.f, sq = 0.f;
#pragma unroll
      for (int fr = 0; fr < 2; ++fr)
#pragma unroll
        for (int r = 0; r < 4; ++r) {
          float v = acc[fr][fc][r];
          mx = fmaxf(mx, v); mn = fminf(mn, v); sm += v; sq = fmaf(v, v, sq);
        }
#pragma unroll
      for (int off = 16; off <= 32; off <<= 1) {
        mx = fmaxf(mx, __shfl_xor(mx, off));
        mn = fminf(mn, __shfl_xor(mn, off));
        sm += __shfl_xor(sm, off);
        sq += __shfl_xor(sq, off);
      }
      if (lane < 16) {
        int col = fc * 16 + lr;
        smx[p][w][col] = mx; smn[p][w][col] = mn; ssm[p][w][col] = sm; ssq[p][w][col] = sq;
      }
    }
    __syncthreads();
    if (tid < CH) {
      float mx = smx[p][0][tid], mn = smn[p][0][tid], sm = ssm[p][0][tid], sq = ssq[p][0][tid];
#pragma unroll
      for (int w2 = 1; w2 < 4; ++w2) {
        mx = fmaxf(mx, smx[p][w2][tid]); mn = fminf(mn, smn[p][w2][tid]);
        sm += ssm[p][w2][tid]; sq += ssq[p][w2][tid];
      }
      z2mx[(size_t)f * CH + tid] = mx;
      z2mn[(size_t)f * CH + tid] = mn;
      psum[(size_t)f * CH + tid] = sm;
      psq[(size_t)f * CH + tid]  = sq;
    }
    cx0 = nx0; cx1 = nx1; cx2 = nx2; cx3 = nx3; cx4 = nx4; cx5 = nx5;
    mu4 = nmu; rs4 = nrs;
  }
}

// bn2 reduce stage 1: 64 blocks x 128 frames, coalesced
__global__ __launch_bounds__(256) void k_red1(const float* __restrict__ psum, const float* __restrict__ psq,
    float* __restrict__ prs, float* __restrict__ prq) {
  __shared__ float s0[2][128], s1[2][128];
  int tid = threadIdx.x, c = tid & 127, half = tid >> 7;
  int f0 = blockIdx.x * 128;
  float sm = 0.f, sq = 0.f;
  for (int fl = half; fl < 128; fl += 2) {
    size_t idx = (size_t)(f0 + fl) * 128 + c;
    sm += psum[idx]; sq += psq[idx];
  }
  s0[half][c] = sm; s1[half][c] = sq;
  __syncthreads();
  if (tid < 128) {
    prs[blockIdx.x * 128 + tid] = s0[0][tid] + s0[1][tid];
    prq[blockIdx.x * 128 + tid] = s1[0][tid] + s1[1][tid];
  }
}

// bn2 reduce stage 2 -> scale/shift
__global__ __launch_bounds__(256) void k_red2(const float* __restrict__ prs, const float* __restrict__ prq,
    const float* __restrict__ w, const float* __restrict__ b, float* __restrict__ st,
    float invM, float eps) {
  __shared__ float s0[2][128], s1[2][128];
  int tid = threadIdx.x, c = tid & 127, half = tid >> 7;
  float sm = 0.f, sq = 0.f;
  for (int g = half; g < 64; g += 2) { sm += prs[g * 128 + c]; sq += prq[g * 128 + c]; }
  s0[half][c] = sm; s1[half][c] = sq;
  __syncthreads();
  if (tid < 128) {
    float tsm = s0[0][tid] + s0[1][tid], tsq = s1[0][tid] + s1[1][tid];
    float mean = tsm * invM;
    float var = tsq * invM - mean * mean;
    float s = w[tid] / sqrtf(var + eps);
    st[tid] = s;
    st[CH + tid] = b[tid] - mean * s;
  }
}

// fused feat + pre-LN + in-proj(layer0): h2(bf16) -> MFMA feat -> LDS LN -> as -> MFMA in-proj
__global__ __launch_bounds__(512) void k_fi(const float* __restrict__ z2mx, const float* __restrict__ z2mn,
    const float* __restrict__ s2t2, const u16* __restrict__ fprojB, const float* __restrict__ fpb,
    const float* __restrict__ plw, const float* __restrict__ plb,
    const u16* __restrict__ inwB_l, const float* __restrict__ inb,
    u16* __restrict__ gate, u16* __restrict__ upd) {
  __shared__ alignas(16) u16 h2s[32 * 128];
  __shared__ float ft[32 * 260];
  __shared__ alignas(16) u16 as[32 * 256];
  int f0 = blockIdx.x * 32, tid = threadIdx.x;
  int lane = tid & 63, w = tid >> 6, lr = lane & 15, kg = lane >> 4;
  {
    int row = tid >> 4, cc = tid & 15, c0 = cc * 8;
    const float* zx = z2mx + (size_t)(f0 + row) * 128 + c0;
    const float* zn = z2mn + (size_t)(f0 + row) * 128 + c0;
    bf16x8 v;
#pragma unroll
    for (int q = 0; q < 8; ++q) {
      int c = c0 + q;
      float s = s2t2[c], t = s2t2[128 + c];
      float z = (s >= 0.f) ? zx[q] : zn[q];
      v[q] = (short)f2bf(fmaxf(0.f, fmaf(s, z, t)));
    }
    *(bf16x8*)&h2s[row * 128 + ((cc ^ (row & 7)) << 3)] = v;
  }
  __syncthreads();
  {
    f32x4 fac[2][2];
#pragma unroll
    for (int fr = 0; fr < 2; ++fr)
#pragma unroll
      for (int fc = 0; fc < 2; ++fc) fac[fr][fc] = (f32x4){0.f, 0.f, 0.f, 0.f};
#pragma unroll
    for (int ks = 0; ks < 4; ++ks) {
      int kc = ks * 4 + kg;
      bf16x8 a0 = *(const bf16x8*)&h2s[lr * 128 + ((kc ^ (lr & 7)) << 3)];
      bf16x8 a1 = *(const bf16x8*)&h2s[(16 + lr) * 128 + ((kc ^ (lr & 7)) << 3)];
#pragma unroll
      for (int fc = 0; fc < 2; ++fc) {
        int d = w * 32 + fc * 16 + lr;
        bf16x8 b = *(const bf16x8*)&fprojB[(size_t)d * 128 + kc * 8];
        fac[0][fc] = MFMA16(a0, b, fac[0][fc], 0, 0, 0);
        fac[1][fc] = MFMA16(a1, b, fac[1][fc], 0, 0, 0);
      }
    }
#pragma unroll
    for (int fr = 0; fr < 2; ++fr)
#pragma unroll
      for (int fc = 0; fc < 2; ++fc) {
        int d = w * 32 + fc * 16 + lr;
        float bias = fpb[d];
#pragma unroll
        for (int r = 0; r < 4; ++r) {
          int row = fr * 16 + kg * 4 + r;
          ft[row * 260 + d] = fac[fr][fc][r] + bias;
        }
      }
  }
  __syncthreads();
  {
    float4 plw4 = ((const float4*)plw)[lane];
    float4 plb4 = ((const float4*)plb)[lane];
#pragma unroll
    for (int q = 0; q < 4; ++q) {
      int row = w * 4 + q;
      float4 v = *(const float4*)&ft[row * 260 + lane * 4];
      float s = v.x + v.y + v.z + v.w;
#pragma unroll
      for (int off = 32; off; off >>= 1) s += __shfl_xor(s, off);
      float mu = s * (1.f / 256.f);
      float4 dd = make_float4(v.x - mu, v.y - mu, v.z - mu, v.w - mu);
      float qq = dd.x*dd.x + dd.y*dd.y + dd.z*dd.z + dd.w*dd.w;
#pragma unroll
      for (int off = 32; off; off >>= 1) qq += __shfl_xor(qq, off);
      float rs = 1.f / sqrtf(qq * (1.f / 256.f) + 1e-5f);
      u16 o[4];
      o[0] = f2bf(fmaf(dd.x * rs, plw4.x, plb4.x));
      o[1] = f2bf(fmaf(dd.y * rs, plw4.y, plb4.y));
      o[2] = f2bf(fmaf(dd.z * rs, plw4.z, plb4.z));
      o[3] = f2bf(fmaf(dd.w * rs, plw4.w, plb4.w));
      int chunk = lane >> 1;
      *(uint2*)&as[row * 256 + ((chunk ^ (row & 7)) << 3) + (lane & 1) * 4] = *(uint2*)o;
    }
  }
  __syncthreads();
  f32x4 acc[2][8];
#pragma unroll
  for (int fr = 0; fr < 2; ++fr)
#pragma unroll
    for (int fc = 0; fc < 8; ++fc) acc[fr][fc] = (f32x4){0.f, 0.f, 0.f, 0.f};
  int colb = w * 128;
#pragma unroll
  for (int ks = 0; ks < 8; ++ks) {
    int kc = ks * 4 + kg;
    int r1 = 16 + lr;
    bf16x8 a0 = *(const bf16x8*)&as[lr * 256 + ((kc ^ (lr & 7)) << 3)];
    bf16x8 a1 = *(const bf16x8*)&as[r1 * 256 + ((kc ^ (r1 & 7)) << 3)];
#pragma unroll
    for (int fc = 0; fc < 8; ++fc) {
      int col = colb + fc * 16 + lr;
      bf16x8 b = *(const bf16x8*)&inwB_l[(size_t)col * 256 + kc * 8];
      acc[0][fc] = MFMA16(a0, b, acc[0][fc], 0, 0, 0);
      acc[1][fc] = MFMA16(a1, b, acc[1][fc], 0, 0, 0);
    }
  }
  bool isGate = (w < 4);
  u16* dst = isGate ? gate : upd;
  int cbOff = isGate ? 0 : 512;
#pragma unroll
  for (int fr = 0; fr < 2; ++fr)
#pragma unroll
    for (int fc = 0; fc < 8; ++fc) {
      int cg = colb + fc * 16 + lr;
      float bias = inb[cg];
      int colOut = cg - cbOff;
#pragma unroll
      for (int r = 0; r < 4; ++r) {
        int frame = f0 + fr * 16 + kg * 4 + r;
        float v = acc[fr][fc][r] + bias;
        float sg = sigmoidf_(v);
        v = isGate ? sg : v * sg;
        dst[(size_t)frame * 512 + colOut] = f2bf(v);
      }
    }
}

// Bu = conv(upd) @ Bm + cbB (masked); 32 frames/block, 4 waves: 2 frame-groups x 2 h-halves
__global__ __launch_bounds__(256) void k_bu(const u16* __restrict__ updB, const u16* __restrict__ BmTd_l,
    const float* __restrict__ cbB_l, const int* __restrict__ lengths, float* __restrict__ bu) {
  __shared__ float part[2][32][16];
  int tid = threadIdx.x, lane = tid & 63, w = tid >> 6;
  int wf = w & 1, hh = w >> 1;
  int f0 = blockIdx.x * 32 + wf * 16;
  int lr = lane & 15, kg = lane >> 4;
  int t = (f0 & 511) + lr;
  const u16* arow = updB + (size_t)(f0 + lr) * 512;
  bool v0 = (t >= 2), v1 = (t >= 1), v3 = (t <= 510);
  const bf16x8 zv = (bf16x8){0,0,0,0,0,0,0,0};
  f32x4 acc = (f32x4){0.f, 0.f, 0.f, 0.f};
#pragma unroll
  for (int ks = 0; ks < 8; ++ks) {
    int kc = hh * 32 + ks * 4 + kg, co = kc * 8;
    bf16x8 a0 = v0 ? *(const bf16x8*)&arow[co - 1024] : zv;
    bf16x8 a1 = v1 ? *(const bf16x8*)&arow[co - 512]  : zv;
    bf16x8 a2 =      *(const bf16x8*)&arow[co];
    bf16x8 a3 = v3 ? *(const bf16x8*)&arow[co + 512]  : zv;
    acc = MFMA16(a0, *(const bf16x8*)&BmTd_l[0 * 8192 + lr * 512 + co], acc, 0, 0, 0);
    acc = MFMA16(a1, *(const bf16x8*)&BmTd_l[1 * 8192 + lr * 512 + co], acc, 0, 0, 0);
    acc = MFMA16(a2, *(const bf16x8*)&BmTd_l[2 * 8192 + lr * 512 + co], acc, 0, 0, 0);
    acc = MFMA16(a3, *(const bf16x8*)&BmTd_l[3 * 8192 + lr * 512 + co], acc, 0, 0, 0);
  }
#pragma unroll
  for (int r = 0; r < 4; ++r) part[hh][wf * 16 + kg * 4 + r][lr] = acc[r];
  __syncthreads();
  int len = lengths[blockIdx.x >> 4];
  for (int i = tid; i < 512; i += 256) {
    int fl = i >> 4, s = i & 15;
    int frame = blockIdx.x * 32 + fl;
    int tt = frame & 511, bi = frame >> 9;
    float val = part[0][fl][s] + part[1][fl][s] + cbB_l[s];
    bu[((size_t)bi * 16 + s) * 512 + tt] = (tt < len) ? val : 0.f;
  }
}

// fused mamba-out(l) + mamba-in(l+1)
__global__ __launch_bounds__(512) void k_mo(const float* __restrict__ bu,
    u16* __restrict__ gateB, u16* __restrict__ updB,
    const u16* __restrict__ albB_l, const u16* __restrict__ outwB_l, const float* __restrict__ outb,
    const u16* __restrict__ inwB_n, const float* __restrict__ inb_n,
    const int* __restrict__ lengths) {
  __shared__ alignas(16) u16 hsb[32 * 40];
  __shared__ alignas(16) u16 vl[32 * 512];
  __shared__ alignas(16) u16 as[32 * 256];
  int f0 = blockIdx.x * 32, tid = threadIdx.x;
  int bb = f0 >> 9, tbase = f0 & 511;
  int len = lengths[bb];
  int lane = tid & 63, w = tid >> 6, lr = lane & 15, kg = lane >> 4;
  for (int i = tid; i < 640; i += 512) ((unsigned int*)hsb)[i] = 0;
  __syncthreads();
#pragma unroll
  for (int q = 0; q < 2; ++q) {
    int s = w * 2 + q;
    const float* src = bu + ((size_t)bb * 16 + s) * 512 + lane * 8;
    float4 v0 = *(const float4*)src, v1 = *(const float4*)(src + 4);
    float p0 = v0.x, p1 = p0 + v0.y, p2 = p1 + v0.z, p3 = p2 + v0.w;
    float p4 = p3 + v1.x, p5 = p4 + v1.y, p6 = p5 + v1.z, p7 = p6 + v1.w;
    float tot = p7;
#pragma unroll
    for (int off = 1; off < 64; off <<= 1) {
      float n = __shfl_up(tot, off);
      if (lane >= off) tot += n;
    }
    float excl = tot - p7;
    int rbase = lane * 8 - tbase;
    if (rbase >= 0 && rbase < 32) {
      hsb[(rbase + 0) * 40 + s] = f2bf(p0 + excl);
      hsb[(rbase + 1) * 40 + s] = f2bf(p1 + excl);
      hsb[(rbase + 2) * 40 + s] = f2bf(p2 + excl);
      hsb[(rbase + 3) * 40 + s] = f2bf(p3 + excl);
      hsb[(rbase + 4) * 40 + s] = f2bf(p4 + excl);
      hsb[(rbase + 5) * 40 + s] = f2bf(p5 + excl);
      hsb[(rbase + 6) * 40 + s] = f2bf(p6 + excl);
      hsb[(rbase + 7) * 40 + s] = f2bf(p7 + excl);
    }
  }
  __syncthreads();
  {
    bf16x8 a0 = *(const bf16x8*)&hsb[lr * 40 + kg * 8];
    bf16x8 a1 = *(const bf16x8*)&hsb[(16 + lr) * 40 + kg * 8];
    f32x4 zero = (f32x4){0.f, 0.f, 0.f, 0.f};
#pragma unroll
    for (int fc = 0; fc < 4; ++fc) {
      int h = w * 64 + fc * 16 + lr;
      bf16x8 b = *(const bf16x8*)&albB_l[h * 32 + kg * 8];
      f32x4 va = MFMA16(a0, b, zero, 0, 0, 0);
      f32x4 vb = MFMA16(a1, b, zero, 0, 0, 0);
      int hck = h >> 3, hlo = h & 7;
#pragma unroll
      for (int fr = 0; fr < 2; ++fr) {
        f32x4 vv = fr ? vb : va;
#pragma unroll
        for (int r = 0; r < 4; ++r) {
          int fl = fr * 16 + kg * 4 + r;
          int frame = f0 + fl;
          float g = bf2f(gateB[(size_t)frame * 512 + h]);
          float val = ((frame & 511) < len) ? vv[r] * g : 0.f;
          vl[fl * 512 + ((hck ^ (fl & 7)) << 3) + hlo] = f2bf(val);
        }
      }
    }
  }
  __syncthreads();
  {
    f32x4 acc2[2][2];
#pragma unroll
    for (int fr = 0; fr < 2; ++fr)
#pragma unroll
      for (int fc = 0; fc < 2; ++fc) acc2[fr][fc] = (f32x4){0.f, 0.f, 0.f, 0.f};
    int db = w * 32;
#pragma unroll
    for (int ks = 0; ks < 16; ++ks) {
      int kc = ks * 4 + kg;
      int r1 = 16 + lr;
      bf16x8 a0 = *(const bf16x8*)&vl[lr * 512 + ((kc ^ (lr & 7)) << 3)];
      bf16x8 a1 = *(const bf16x8*)&vl[r1 * 512 + ((kc ^ (r1 & 7)) << 3)];
#pragma unroll
      for (int fc = 0; fc < 2; ++fc) {
        int d = db + fc * 16 + lr;
        bf16x8 b = *(const bf16x8*)&outwB_l[(size_t)d * 512 + kc * 8];
        acc2[0][fc] = MFMA16(a0, b, acc2[0][fc], 0, 0, 0);
        acc2[1][fc] = MFMA16(a1, b, acc2[1][fc], 0, 0, 0);
      }
    }
#pragma unroll
    for (int fr = 0; fr < 2; ++fr)
#pragma unroll
      for (int fc = 0; fc < 2; ++fc) {
        int d = db + fc * 16 + lr;
        float bias = outb[d];
        int dck = d >> 3, dlo = d & 7;
#pragma unroll
        for (int r = 0; r < 4; ++r) {
          int row = fr * 16 + kg * 4 + r;
          as[row * 256 + ((dck ^ (row & 7)) << 3) + dlo] = f2bf(acc2[fr][fc][r] + bias);
        }
      }
  }
  __syncthreads();
  f32x4 acc[2][8];
#pragma unroll
  for (int fr = 0; fr < 2; ++fr)
#pragma unroll
    for (int fc = 0; fc < 8; ++fc) acc[fr][fc] = (f32x4){0.f, 0.f, 0.f, 0.f};
  int colb = w * 128;
#pragma unroll
  for (int ks = 0; ks < 8; ++ks) {
    int kc = ks * 4 + kg;
    int r1 = 16 + lr;
    bf16x8 a0 = *(const bf16x8*)&as[lr * 256 + ((kc ^ (lr & 7)) << 3)];
    bf16x8 a1 = *(const bf16x8*)&as[r1 * 256 + ((kc ^ (r1 & 7)) << 3)];
#pragma unroll
    for (int fc = 0; fc < 8; ++fc) {
      int col = colb + fc * 16 + lr;
      bf16x8 b = *(const bf16x8*)&inwB_n[(size_t)col * 256 + kc * 8];
      acc[0][fc] = MFMA16(a0, b, acc[0][fc], 0, 0, 0);
      acc[1][fc] = MFMA16(a1, b, acc[1][fc], 0, 0, 0);
    }
  }
  bool isGate = (w < 4);
  u16* dst = isGate ? gateB : updB;
  int cbOff = isGate ? 0 : 512;
#pragma unroll
  for (int fr = 0; fr < 2; ++fr)
#pragma unroll
    for (int fc = 0; fc < 8; ++fc) {
      int cg = colb + fc * 16 + lr;
      float bias = inb_n[cg];
      int colOut = cg - cbOff;
#pragma unroll
      for (int r = 0; r < 4; ++r) {
        int frame = f0 + fr * 16 + kg * 4 + r;
        float v = acc[fr][fc][r] + bias;
        float sg = sigmoidf_(v);
        v = isGate ? sg : v * sg;
        dst[(size_t)frame * 512 + colOut] = f2bf(v);
      }
    }
}

// final-layer out-proj (standalone, with fused scan prologue) -> sout f32
__global__ __launch_bounds__(256) void k_out(const float* __restrict__ bu, const u16* __restrict__ gateB,
    const u16* __restrict__ albB_l, const u16* __restrict__ outwB_l, const float* __restrict__ outb,
    const int* __restrict__ lengths, float* __restrict__ sout) {
  __shared__ alignas(16) u16 hsb[32 * 40];
  __shared__ alignas(16) u16 vl[32 * 512];
  int f0 = blockIdx.x * 32, tid = threadIdx.x;
  int bb = f0 >> 9, tbase = f0 & 511;
  int len = lengths[bb];
  int lane = tid & 63, w = tid >> 6, lr = lane & 15, kg = lane >> 4;
  for (int i = tid; i < 640; i += 256) ((unsigned int*)hsb)[i] = 0;
  __syncthreads();
#pragma unroll
  for (int q = 0; q < 4; ++q) {
    int s = w * 4 + q;
    const float* src = bu + ((size_t)bb * 16 + s) * 512 + lane * 8;
    float4 v0 = *(const float4*)src, v1 = *(const float4*)(src + 4);
    float p0 = v0.x, p1 = p0 + v0.y, p2 = p1 + v0.z, p3 = p2 + v0.w;
    float p4 = p3 + v1.x, p5 = p4 + v1.y, p6 = p5 + v1.z, p7 = p6 + v1.w;
    float tot = p7;
#pragma unroll
    for (int off = 1; off < 64; off <<= 1) {
      float n = __shfl_up(tot, off);
      if (lane >= off) tot += n;
    }
    float excl = tot - p7;
    int rbase = lane * 8 - tbase;
    if (rbase >= 0 && rbase < 32) {
      hsb[(rbase + 0) * 40 + s] = f2bf(p0 + excl);
      hsb[(rbase + 1) * 40 + s] = f2bf(p1 + excl);
      hsb[(rbase + 2) * 40 + s] = f2bf(p2 + excl);
      hsb[(rbase + 3) * 40 + s] = f2bf(p3 + excl);
      hsb[(rbase + 4) * 40 + s] = f2bf(p4 + excl);
      hsb[(rbase + 5) * 40 + s] = f2bf(p5 + excl);
      hsb[(rbase + 6) * 40 + s] = f2bf(p6 + excl);
      hsb[(rbase + 7) * 40 + s] = f2bf(p7 + excl);
    }
  }
  __syncthreads();
  {
    bf16x8 a0 = *(const bf16x8*)&hsb[lr * 40 + kg * 8];
    bf16x8 a1 = *(const bf16x8*)&hsb[(16 + lr) * 40 + kg * 8];
    f32x4 zero = (f32x4){0.f, 0.f, 0.f, 0.f};
#pragma unroll
    for (int fc = 0; fc < 8; ++fc) {
      int h = w * 128 + fc * 16 + lr;
      bf16x8 b = *(const bf16x8*)&albB_l[h * 32 + kg * 8];
      f32x4 va = MFMA16(a0, b, zero, 0, 0, 0);
      f32x4 vb = MFMA16(a1, b, zero, 0, 0, 0);
      int hck = h >> 3, hlo = h & 7;
#pragma unroll
      for (int fr = 0; fr < 2; ++fr) {
        f32x4 vv = fr ? vb : va;
#pragma unroll
        for (int r = 0; r < 4; ++r) {
          int fl = fr * 16 + kg * 4 + r;
          int frame = f0 + fl;
          float g = bf2f(gateB[(size_t)frame * 512 + h]);
          float val = ((frame & 511) < len) ? vv[r] * g : 0.f;
          vl[fl * 512 + ((hck ^ (fl & 7)) << 3) + hlo] = f2bf(val);
        }
      }
    }
  }
  __syncthreads();
  f32x4 acc[2][4];
#pragma unroll
  for (int fr = 0; fr < 2; ++fr)
#pragma unroll
    for (int fc = 0; fc < 4; ++fc) acc[fr][fc] = (f32x4){0.f, 0.f, 0.f, 0.f};
  int db = w * 64;
#pragma unroll
  for (int ks = 0; ks < 16; ++ks) {
    int kc = ks * 4 + kg;
    int r1 = 16 + lr;
    bf16x8 a0 = *(const bf16x8*)&vl[lr * 512 + ((kc ^ (lr & 7)) << 3)];
    bf16x8 a1 = *(const bf16x8*)&vl[r1 * 512 + ((kc ^ (r1 & 7)) << 3)];
#pragma unroll
    for (int fc = 0; fc < 4; ++fc) {
      int d = db + fc * 16 + lr;
      bf16x8 b = *(const bf16x8*)&outwB_l[(size_t)d * 512 + kc * 8];
      acc[0][fc] = MFMA16(a0, b, acc[0][fc], 0, 0, 0);
      acc[1][fc] = MFMA16(a1, b, acc[1][fc], 0, 0, 0);
    }
  }
#pragma unroll
  for (int fr = 0; fr < 2; ++fr)
#pragma unroll
    for (int fc = 0; fc < 4; ++fc) {
      int d = db + fc * 16 + lr;
      float bias = outb[d];
#pragma unroll
      for (int r = 0; r < 4; ++r) {
        int frame = f0 + fr * 16 + kg * 4 + r;
        sout[(size_t)frame * 256 + d] = acc[fr][fc][r] + bias;
      }
    }
}

// post-LN + masked pool stage 1: grid 128 (16 b x 8 chunks of 64 frames) -> partial sums
__global__ __launch_bounds__(512) void k_pp1(const float* __restrict__ seq, const int* __restrict__ lengths,
    const float* __restrict__ w, const float* __restrict__ b, float* __restrict__ ppart) {
  __shared__ float4 part[8][64];
  int bb = blockIdx.x >> 3, ck = blockIdx.x & 7;
  int tid = threadIdx.x, lane = tid & 63, wv = tid >> 6;
  int len = lengths[bb];
  float4 w4 = ((const float4*)w)[lane], b4 = ((const float4*)b)[lane];
  float4 pacc = make_float4(0.f, 0.f, 0.f, 0.f);
#pragma unroll
  for (int it = 0; it < 8; ++it) {
    int t = ck * 64 + it * 8 + wv;
    float4 v = ((const float4*)(seq + ((size_t)bb * 512 + t) * DD))[lane];
    float s = v.x + v.y + v.z + v.w;
#pragma unroll
    for (int off = 32; off; off >>= 1) s += __shfl_xor(s, off);
    float mu = s * (1.f / 256.f);
    float4 dd = make_float4(v.x - mu, v.y - mu, v.z - mu, v.w - mu);
    float q = dd.x*dd.x + dd.y*dd.y + dd.z*dd.z + dd.w*dd.w;
#pragma unroll
    for (int off = 32; off; off >>= 1) q += __shfl_xor(q, off);
    float rs = 1.f / sqrtf(q * (1.f / 256.f) + 1e-5f);
    if (t < len) {
      pacc.x += fmaf(dd.x * rs, w4.x, b4.x);
      pacc.y += fmaf(dd.y * rs, w4.y, b4.y);
      pacc.z += fmaf(dd.z * rs, w4.z, b4.z);
      pacc.w += fmaf(dd.w * rs, w4.w, b4.w);
    }
  }
  part[wv][lane] = pacc;
  __syncthreads();
  if (tid < 64) {
    float4 a = part[0][tid];
#pragma unroll
    for (int w2 = 1; w2 < 8; ++w2) {
      float4 p = part[w2][tid];
      a.x += p.x; a.y += p.y; a.z += p.z; a.w += p.w;
    }
    ((float4*)(ppart + (size_t)blockIdx.x * DD))[tid] = a;
  }
}

// pool stage 2: combine 8 chunk partials, divide by len
__global__ __launch_bounds__(256) void k_pp2(const float* __restrict__ ppart, const int* __restrict__ lengths,
    float* __restrict__ pooled) {
  int bb = blockIdx.x, d = threadIdx.x;
  float a = 0.f;
#pragma unroll
  for (int ck = 0; ck < 8; ++ck) a += ppart[(size_t)(bb * 8 + ck) * DD + d];
  pooled[(size_t)bb * DD + d] = a / (float)max(lengths[bb], 1);
}

// wave-per-output MLP, float4 K-loads: out[16][Nout] = act(in[16][K] @ W^T + b); grid = Nout/4
__global__ __launch_bounds__(256) void k_mlp(const float* __restrict__ in, const float* __restrict__ W,
    const float* __restrict__ bias, float* __restrict__ out, int K, int Nout, int act) {
  __shared__ float lin[16 * 1024];
  int tid = threadIdx.x, lane = tid & 63, w = tid >> 6;
  for (int i = tid; i < 16 * K / 4; i += 256) ((float4*)lin)[i] = ((const float4*)in)[i];
  __syncthreads();
  int o = blockIdx.x * 4 + w;
  const float4* wr4 = (const float4*)(W + (size_t)o * K);
  float acc[16];
#pragma unroll
  for (int r = 0; r < 16; ++r) acc[r] = 0.f;
  for (int k4 = lane; k4 < K / 4; k4 += 64) {
    float4 wv = wr4[k4];
    int kb = k4 * 4;
#pragma unroll
    for (int r = 0; r < 16; ++r) {
      float4 lv = *(const float4*)&lin[r * K + kb];
      acc[r] = fmaf(lv.x, wv.x, fmaf(lv.y, wv.y, fmaf(lv.z, wv.z, fmaf(lv.w, wv.w, acc[r]))));
    }
  }
#pragma unroll
  for (int r = 0; r < 16; ++r) {
#pragma unroll
    for (int off = 32; off; off >>= 1) acc[r] += __shfl_xor(acc[r], off);
  }
  if (lane < 16) {
    float v = 0.f;
#pragma unroll
    for (int r = 0; r < 16; ++r) if (lane == r) v = acc[r];
    v += bias[o];
    if (act) v = geluf_(v);
    out[(size_t)lane * Nout + o] = v;
  }
}

// L2 normalize rows of e[16][512]
__global__ __launch_bounds__(256) void k_norm(const float* __restrict__ e, float* __restrict__ out) {
  __shared__ float sc[4];
  int b = blockIdx.x, tid = threadIdx.x;
  float v0 = e[(size_t)b * 512 + tid], v1 = e[(size_t)b * 512 + 256 + tid];
  float ss = red256(v0 * v0 + v1 * v1, tid, sc);
  float nrm = fmaxf(sqrtf(ss), 1e-12f);
  out[(size_t)b * 512 + tid] = v0 / nrm;
  out[(size_t)b * 512 + 256 + tid] = v1 / nrm;
}

// ---------------- launch ----------------

extern "C" void kernel_launch(void* const* d_in, const int* in_sizes, int n_in,
                              void* d_out, int out_size, void* d_ws, size_t ws_size,
                              hipStream_t stream) {
  const float* x         = (const float*)d_in[0];
  const int*   lengths   = (const int*)d_in[1];
  const float* conv1_w   = (const float*)d_in[2];
  const float* bn1_w     = (const float*)d_in[3];
  const float* bn1_b     = (const float*)d_in[4];
  const float* conv2_w   = (const float*)d_in[5];
  const float* bn2_w     = (const float*)d_in[6];
  const float* bn2_b     = (const float*)d_in[7];
  const float* fproj_w   = (const float*)d_in[8];
  const float* fproj_b   = (const float*)d_in[9];
  const float* pre_ln_w  = (const float*)d_in[10];
  const float* pre_ln_b  = (const float*)d_in[11];
  const float* in_w      = (const float*)d_in[12];
  const float* in_b      = (const float*)d_in[13];
  const float* conv_w    = (const float*)d_in[14];
  const float* conv_b    = (const float*)d_in[15];
  const float* A         = (const float*)d_in[16];
  const float* Bm        = (const float*)d_in[17];
  const float* out_w     = (const float*)d_in[18];
  const float* out_b     = (const float*)d_in[19];
  const float* post_ln_w = (const float*)d_in[20];
  const float* post_ln_b = (const float*)d_in[21];
  const float* m1_w      = (const float*)d_in[22];
  const float* m1_b      = (const float*)d_in[23];
  const float* m2_w      = (const float*)d_in[24];
  const float* m2_b      = (const float*)d_in[25];
  const float* m3_w      = (const float*)d_in[26];
  const float* m3_b      = (const float*)d_in[27];
  float* outp = (float*)d_out;

  float* wsf = (float*)d_ws;
  size_t o = 0;
  auto F32 = [&](size_t n) { float* p = wsf + o; o += (n + 63) & ~(size_t)63; return p; };
  float* psum   = F32(1048576);
  float* psq    = F32(1048576);
  float* z2mx   = F32(1048576);
  float* z2mn   = F32(1048576);
  float* msd    = F32(65536);
  float* pstat  = F32(16384);
  float* cc     = F32(512);
  float* s2t2   = F32(256);
  float* prs    = F32(8192);
  float* prq    = F32(8192);
  u16*   W2B    = (u16*)F32(8192);      // 16384 bf16
  u16*   fprojB = (u16*)F32(16384);     // 32768 bf16
  u16*   inwB   = (u16*)F32(524288);    // 1048576 bf16
  u16*   outwB  = (u16*)F32(262144);    // 524288 bf16
  u16*   albB   = (u16*)F32(32768);     // 65536 bf16
  u16*   BmTd   = (u16*)F32(65536);     // 131072 bf16
  float* cbB    = F32(64);
  float* seqA   = F32(2097152);
  u16*   gateB  = (u16*)F32(2097152);   // 8192x512 bf16
  u16*   updB   = (u16*)F32(2097152);
  float* buv    = F32(131072);
  float* ppart  = F32(32768);
  float* pooled = F32(4096);
  float* e1     = F32(16384);
  float* e2     = F32(16384);
  float* e3     = F32(8192);
  if (ws_size < o * sizeof(float)) return;

  const float invM = 1.f / (float)(NFRM * NPT);

  k_prep<<<2416, 256, 0, stream>>>(conv2_w, fproj_w, in_w, out_w, A, Bm, conv_w, conv_b,
                                   W2B, fprojB, inwB, outwB, albB, BmTd, cbB);
  k_mom<<<2048, 256, 0, stream>>>(x, msd, pstat);
  k_stats2<<<1, 256, 0, stream>>>(pstat, conv1_w, bn1_w, bn1_b, cc);
  k2_main<<<NFRM / 4, 256, 0, stream>>>(x, (const float4*)cc, (const float4*)msd, W2B,
                                        z2mx, z2mn, psum, psq);
  k_red1<<<64, 256, 0, stream>>>(psum, psq, prs, prq);
  k_red2<<<1, 256, 0, stream>>>(prs, prq, bn2_w, bn2_b, s2t2, invM, 1e-5f);
  k_fi<<<NFRM / 32, 512, 0, stream>>>(z2mx, z2mn, s2t2, fprojB, fproj_b, pre_ln_w, pre_ln_b,
                                      inwB, in_b, gateB, updB);

  for (int l = 0; l < 3; ++l) {
    k_bu<<<NFRM / 32, 256, 0, stream>>>(updB, BmTd + (size_t)l * 32768, cbB + l * 16, lengths, buv);
    k_mo<<<NFRM / 32, 512, 0, stream>>>(buv, gateB, updB,
                                        albB + (size_t)l * 16384, outwB + (size_t)l * 131072,
                                        out_b + l * 256,
                                        inwB + (size_t)(l + 1) * 262144, in_b + (l + 1) * 1024,
                                        lengths);
  }
  k_bu<<<NFRM / 32, 256, 0, stream>>>(updB, BmTd + (size_t)3 * 32768, cbB + 3 * 16, lengths, buv);
  k_out<<<NFRM / 32, 256, 0, stream>>>(buv, gateB, albB + (size_t)3 * 16384,
                                       outwB + (size_t)3 * 131072, out_b + 3 * 256, lengths, seqA);
  k_pp1<<<128, 512, 0, stream>>>(seqA, lengths, post_ln_w, post_ln_b, ppart);
  k_pp2<<<16, 256, 0, stream>>>(ppart, lengths, pooled);
  k_mlp<<<256, 256, 0, stream>>>(pooled, m1_w, m1_b, e1, 256, 1024, 1);
  k_mlp<<<256, 256, 0, stream>>>(e1, m2_w, m2_b, e2, 1024, 1024, 1);
  k_mlp<<<128, 256, 0, stream>>>(e2, m3_w, m3_b, e3, 1024, 512, 0);
  k_norm<<<16, 256, 0, stream>>>(e3, outp);
}